// Round 8
// baseline (1180.157 us; speedup 1.0000x reference)
//
#include <hip/hip_runtime.h>
#include <math.h>

#define TOK_L 3073
#define EMB 768
#define NH 12
#define DH 64
#define BATCH 2
#define QKVS 2304
#define HSZ ((size_t)BATCH * TOK_L * EMB)   // 4,720,128
#define MHC ((size_t)BATCH * TOK_L * NH)    // 73,752

typedef __bf16 bf16;
typedef __bf16 v8bf __attribute__((ext_vector_type(8)));
typedef __bf16 v4bf __attribute__((ext_vector_type(4)));
typedef float  v4f  __attribute__((ext_vector_type(4)));

__device__ __forceinline__ v8bf zero8() {
    v8bf v;
    #pragma unroll
    for (int i = 0; i < 8; i++) v[i] = (bf16)0.f;
    return v;
}
__device__ __forceinline__ v4f zero4() {
    v4f v; v[0] = 0.f; v[1] = 0.f; v[2] = 0.f; v[3] = 0.f; return v;
}
__device__ __forceinline__ float gelu_f(float x) {
    return 0.5f * x * (1.0f + erff(x * 0.70710678118654752f));
}
// async global->LDS: lane l writes 16B at (uniform base) + l*16
__device__ __forceinline__ void gload16(const bf16* g, bf16* l) {
    __builtin_amdgcn_global_load_lds(
        (const __attribute__((address_space(1))) void*)g,
        (__attribute__((address_space(3))) void*)l, 16, 0, 0);
}

// ---------------------------------------------------------------------------
// Mega weight-prep: 12 transpose-converts + patch_w cvt. grid = 14592.
// ---------------------------------------------------------------------------
__device__ __forceinline__ void convT_tile(const float* __restrict__ src,
                                           bf16* __restrict__ dst,
                                           int K, int N, int tx, int ty)
{
    __shared__ float t[32][33];
    int n0 = tx * 32, k0 = ty * 32;
    int r = threadIdx.x >> 3, c4 = (threadIdx.x & 7) * 4;
    float4 v = *(const float4*)(src + (size_t)(k0 + r) * N + n0 + c4);
    t[r][c4 + 0] = v.x; t[r][c4 + 1] = v.y; t[r][c4 + 2] = v.z; t[r][c4 + 3] = v.w;
    __syncthreads();
    v4bf o;
    o[0] = (bf16)t[c4 + 0][r]; o[1] = (bf16)t[c4 + 1][r];
    o[2] = (bf16)t[c4 + 2][r]; o[3] = (bf16)t[c4 + 3][r];
    *(v4bf*)(dst + (size_t)(n0 + r) * K + k0 + c4) = o;
}

__global__ __launch_bounds__(256) void prep_weights(
    const float* __restrict__ wq, const float* __restrict__ wk,
    const float* __restrict__ wv, const float* __restrict__ wo,
    const float* __restrict__ w1, const float* __restrict__ w2,
    const float* __restrict__ patch_w,
    bf16* __restrict__ qkv_t0, bf16* __restrict__ wo_t0,
    bf16* __restrict__ w1_t, bf16* __restrict__ w2_t, bf16* __restrict__ pw_b)
{
    int bid = blockIdx.x;
    if (bid >= 13824) {
        int i = ((bid - 13824) * 256 + threadIdx.x) * 4;
        float4 v = *(const float4*)(patch_w + i);
        v4bf o; o[0] = (bf16)v.x; o[1] = (bf16)v.y; o[2] = (bf16)v.z; o[3] = (bf16)v.w;
        *(v4bf*)(pw_b + i) = o;
        return;
    }
    int layer = bid / 6912, t = bid % 6912;
    if (t < 1728) {
        int m = t / 576, tt = t % 576;
        const float* src = (m == 0 ? wq : m == 1 ? wk : wv) + (size_t)layer * 589824;
        bf16* dst = qkv_t0 + (size_t)layer * QKVS * 768 + (size_t)m * 589824;
        convT_tile(src, dst, 768, 768, tt % 24, tt / 24);
    } else if (t < 2304) {
        int tt = t - 1728;
        convT_tile(wo + (size_t)layer * 589824, wo_t0 + (size_t)layer * 589824,
                   768, 768, tt % 24, tt / 24);
    } else if (t < 4608) {
        int tt = t - 2304;
        convT_tile(w1 + (size_t)layer * 2359296, w1_t + (size_t)layer * 2359296,
                   768, 3072, tt % 96, tt / 96);
    } else {
        int tt = t - 4608;
        convT_tile(w2 + (size_t)layer * 2359296, w2_t + (size_t)layer * 2359296,
                   3072, 768, tt % 24, tt / 24);
    }
}

// concat q/k/v biases -> bqkv[layer][2304]; also init cls rows of h. grid 18.
__global__ __launch_bounds__(256) void prep_small(const float* __restrict__ bq,
    const float* __restrict__ bk, const float* __restrict__ bv, float* __restrict__ d,
    const float* __restrict__ cls, const float* __restrict__ pos, float* __restrict__ h)
{
    int i = blockIdx.x * 256 + threadIdx.x;
    if (i < 2 * QKVS) {
        int layer = i / QKVS, j = i % QKVS;
        const float* s = (j < 768) ? bq : (j < 1536) ? bk : bv;
        d[i] = s[(size_t)layer * 768 + (j & 767)];
    }
    if (i < 2 * 768) {
        int b = i / 768, e = i % 768;
        h[(size_t)b * TOK_L * EMB + e] = cls[e] + pos[e];
    }
}

// ---------------------------------------------------------------------------
// Patch gather: x (B,1,48,256,256) fp32 -> Xp (B*3072, 1024) bf16
// ---------------------------------------------------------------------------
__global__ __launch_bounds__(256) void gather_patches(const float* __restrict__ x,
                                                      bf16* __restrict__ Xp) {
    int p = blockIdx.x;
    int b = p / 3072, pp = p % 3072;
    int px = pp >> 8, py = (pp >> 4) & 15, pz = pp & 15;
    for (int k = threadIdx.x; k < 1024; k += 256) {
        int pd = k >> 8, ph = (k >> 4) & 15, pw = k & 15;
        size_t src = ((size_t)(b * 48 + px * 4 + pd)) * 65536
                   + (size_t)(py * 16 + ph) * 256 + (size_t)(pz * 16 + pw);
        Xp[(size_t)p * 1024 + k] = (bf16)x[src];
    }
}

// ---------------------------------------------------------------------------
// bf16 MFMA GEMM: 128xBN tile, BK=32, fragment-order LDS staging (conflict-
// free ds_read_b128 at fragbase + lane*16), DOUBLE-BUFFERED async K-loop:
//   barrier (drains stage issued one compute-step ago) -> issue next stage
//   into other buffer -> compute current. 2D grid (n fast).
// flags: 1 acc into Cf, 2 gelu, 4 patch row remap (+pos fuse), 8 bf16 out
// ---------------------------------------------------------------------------
template<int BN>
__global__ __launch_bounds__(256) void gemm_bf16(
    const bf16* __restrict__ A, const bf16* __restrict__ Bt,
    const float* __restrict__ bias, float* __restrict__ Cf,
    bf16* __restrict__ Cb, int M, int N, int K, int flags,
    const float* __restrict__ pos)
{
    __shared__ bf16 As[2][128 * 32];
    __shared__ bf16 Bs[2][BN * 32];
    const int tid = threadIdx.x;
    const int lane = tid & 63, wid = tid >> 6;
    const int ln15 = lane & 15, q4 = lane >> 4;
    const int m0 = blockIdx.y * 128, n0 = blockIdx.x * BN;
    const int wm = (wid & 1) * 64, wn = (wid >> 1) * (BN / 2);
    const int NF = BN / 32;
    const int lrow = lane & 15, lchunk = lane >> 4;

    auto stage = [&](int k0, int bufi) {
        #pragma unroll
        for (int fi = 0; fi < 2; fi++) {
            int f = wid * 2 + fi;
            int gm = m0 + f * 16 + lrow; if (gm >= M) gm = M - 1;
            gload16(A + (size_t)gm * K + k0 + lchunk * 8, As[bufi] + f * 512);
        }
        if (BN == 128) {
            #pragma unroll
            for (int fi = 0; fi < 2; fi++) {
                int f = wid * 2 + fi;
                gload16(Bt + (size_t)(n0 + f * 16 + lrow) * K + k0 + lchunk * 8,
                        Bs[bufi] + f * 512);
            }
        } else {
            gload16(Bt + (size_t)(n0 + wid * 16 + lrow) * K + k0 + lchunk * 8,
                    Bs[bufi] + wid * 512);
        }
    };

    v4f acc[4][NF];
    #pragma unroll
    for (int i = 0; i < 4; i++)
        #pragma unroll
        for (int j = 0; j < NF; j++) acc[i][j] = zero4();

    const int nsteps = K >> 5;
    stage(0, 0);
    for (int s = 0; s < nsteps; s++) {
        const int cur = s & 1;
        __syncthreads();                       // stage(s) landed
        if (s + 1 < nsteps) stage((s + 1) << 5, cur ^ 1);
        v8bf af[4], bfr[NF];
        #pragma unroll
        for (int mt = 0; mt < 4; mt++)
            af[mt] = *(const v8bf*)(As[cur] + ((wid & 1) * 4 + mt) * 512 + lane * 8);
        #pragma unroll
        for (int nt = 0; nt < NF; nt++)
            bfr[nt] = *(const v8bf*)(Bs[cur] + ((wid >> 1) * NF + nt) * 512 + lane * 8);
        #pragma unroll
        for (int mt = 0; mt < 4; mt++)
            #pragma unroll
            for (int nt = 0; nt < NF; nt++)
                acc[mt][nt] = __builtin_amdgcn_mfma_f32_16x16x32_bf16(af[mt], bfr[nt], acc[mt][nt], 0, 0, 0);
    }
    #pragma unroll
    for (int mt = 0; mt < 4; mt++) {
        #pragma unroll
        for (int nt = 0; nt < NF; nt++) {
            #pragma unroll
            for (int g = 0; g < 4; g++) {
                int row = m0 + wm + mt * 16 + q4 * 4 + g;
                if (row >= M) continue;
                int col = n0 + wn + nt * 16 + ln15;
                float v = acc[mt][nt][g] + bias[col];
                if (flags & 2) v = gelu_f(v);
                size_t crow;
                if (flags & 4) {
                    int rowp = row % 3072;
                    crow = (size_t)(row + row / 3072 + 1);
                    v += pos[(size_t)(rowp + 1) * EMB + col];
                } else crow = (size_t)row;
                size_t ci = crow * (size_t)N + col;
                if (flags & 8) Cb[ci] = (bf16)v;
                else { if (flags & 1) v += Cf[ci]; Cf[ci] = v; }
            }
        }
    }
}

// ---------------------------------------------------------------------------
// LayerNorm over last dim (768), fp32 in -> bf16 out.
// ---------------------------------------------------------------------------
__global__ __launch_bounds__(256) void layernorm_kernel(
    const float* __restrict__ x, const float* __restrict__ g,
    const float* __restrict__ bb, bf16* __restrict__ y, int nrows)
{
    int row = blockIdx.x;
    if (row >= nrows) return;
    int tid = threadIdx.x;
    const float* xr = x + (size_t)row * EMB;
    float v0 = xr[tid], v1 = xr[tid + 256], v2 = xr[tid + 512];
    __shared__ float red[256];
    red[tid] = v0 + v1 + v2;
    __syncthreads();
    for (int o = 128; o > 0; o >>= 1) { if (tid < o) red[tid] += red[tid + o]; __syncthreads(); }
    float mu = red[0] * (1.f / 768.f);
    __syncthreads();
    float d0 = v0 - mu, d1 = v1 - mu, d2 = v2 - mu;
    red[tid] = d0 * d0 + d1 * d1 + d2 * d2;
    __syncthreads();
    for (int o = 128; o > 0; o >>= 1) { if (tid < o) red[tid] += red[tid + o]; __syncthreads(); }
    float rs = rsqrtf(red[0] * (1.f / 768.f) + 1e-5f);
    bf16* yr = y + (size_t)row * EMB;
    yr[tid]       = (bf16)(d0 * rs * g[tid]       + bb[tid]);
    yr[tid + 256] = (bf16)(d1 * rs * g[tid + 256] + bb[tid + 256]);
    yr[tid + 512] = (bf16)(d2 * rs * g[tid + 512] + bb[tid + 512]);
}

// ---------------------------------------------------------------------------
// Pack V per branch-slot in PV B-FRAGMENT order:
// Vt[(yy*24+bh)*12 + kt][frag(dt,ks)][lane][8] — attn reads contiguous 1KB.
// ---------------------------------------------------------------------------
__global__ __launch_bounds__(256) void pack_vt(const bf16* __restrict__ qkv,
                                               bf16* __restrict__ Vt)
{
    __shared__ bf16 t[64 * 65];
    int yy = blockIdx.y;
    int br, seg;
    if (yy < 5)       { br = 0; seg = yy; }
    else if (yy < 8)  { br = 1; seg = yy - 5; }
    else if (yy < 10) { br = 2; seg = yy - 8; }
    else if (yy == 10){ br = 3; seg = 0; }
    else              { br = 4; seg = 0; }
    const int r = 1 << br, w = 768 << br;
    const int gsz = (NH + r - 1) / r;
    const int bh = blockIdx.z;
    const int b = bh / NH, hd = bh % NH;
    const int off = hd / gsz;
    const int kbase = seg * w + off;
    const int kt = blockIdx.x;
    const int tid = threadIdx.x;
    const int dq = (tid & 7) * 8;
    #pragma unroll
    for (int p = 0; p < 2; p++) {
        int jl = (tid >> 3) + p * 32;
        int pk = kbase + (kt * 64 + jl) * r;
        v8bf val = (pk < TOK_L)
            ? *(const v8bf*)(qkv + (size_t)(b * TOK_L + pk) * QKVS + 1536 + hd * DH + dq)
            : zero8();
        #pragma unroll
        for (int i = 0; i < 8; i++) t[jl * 65 + dq + i] = val[i];
    }
    __syncthreads();
    size_t base = ((size_t)(yy * 24 + bh) * 12 + kt) * 4096;
    #pragma unroll
    for (int p = 0; p < 2; p++) {
        int cc = p * 256 + tid;                 // chunk 0..511
        int f = cc >> 6, lanei = cc & 63;
        int dt = f >> 1, ks = f & 1;
        int dh = dt * 16 + (lanei & 15);
        int k0e = ks * 32 + (lanei >> 4) * 8;
        v8bf o;
        #pragma unroll
        for (int i = 0; i < 8; i++) o[i] = t[(k0e + i) * 65 + dh];
        *(v8bf*)(Vt + base + (size_t)cc * 8) = o;
    }
}

// ---------------------------------------------------------------------------
// MFMA dilated attention. K tiles staged async in B-fragment order (double-
// buffered, conflict-free reads); P scratch in A-fragment order; V read from
// fragment-order Vt (contiguous global). Padded keys masked analytically.
// ---------------------------------------------------------------------------
__global__ __launch_bounds__(256) void attn_mfma(
    const bf16* __restrict__ qkv, const bf16* __restrict__ Vt,
    bf16* __restrict__ oac, bf16* __restrict__ obr, float* __restrict__ lse5)
{
    __shared__ bf16 kl[2 * 4096];        // 2 buffers x 8 frags x 512
    __shared__ bf16 pl[4][2048];         // per-wave: 4 frags x 512
    const int tid = threadIdx.x;
    const int lane = tid & 63, wid = tid >> 6;
    const int ln15 = lane & 15, q4 = lane >> 4;
    const int lrow = lane & 15, lchunk = lane >> 4;
    const int bid = blockIdx.x;
    const int xcd = bid & 7, rest = bid >> 3;
    const int slot = rest / 6, t = rest - slot * 6;
    const int g = (slot << 3) | xcd;          // 0..287
    const int yy = g / 24, bh = g - yy * 24;
    int br, seg;
    if (yy < 5)       { br = 0; seg = yy; }
    else if (yy < 8)  { br = 1; seg = yy - 5; }
    else if (yy < 10) { br = 2; seg = yy - 8; }
    else if (yy == 10){ br = 3; seg = 0; }
    else              { br = 4; seg = 0; }
    const int r = 1 << br, w = 768 << br;
    const int gsz = (NH + r - 1) / r;
    const int b = bh / NH, hd = bh % NH;
    const int off = hd / gsz;
    const int sbase = seg * w + off;
    if (sbase + (t * 128) * r >= TOK_L) return;     // block-uniform early exit

    int n_valid = (TOK_L - sbase + r - 1) / r;
    if (n_valid > 768) n_valid = 768;
    const int kt_lim = (n_valid + 63) >> 6;
    const float pad_add = (float)(768 - n_valid);
    const int qoff = t * 128 + wid * 32;
    const bool wactive = (sbase + qoff * r) < TOK_L;

    const bf16* qb_ = qkv + hd * DH;
    const bf16* kb_ = qkv + 768 + hd * DH;

    // stage K tile ktv into buffer bufi, fragment order (frag = nt*2+ks)
    auto stageK = [&](int ktv, int bufi) {
        #pragma unroll
        for (int fi = 0; fi < 2; fi++) {
            int f = wid * 2 + fi;
            int pk = sbase + (ktv * 64 + (f >> 1) * 16 + lrow) * r;
            if (pk >= TOK_L) pk = 0;                // garbage row; masked later
            gload16(kb_ + (size_t)(b * TOK_L + pk) * QKVS + (f & 1) * 32 + lchunk * 8,
                    kl + bufi * 4096 + f * 512);
        }
    };

    // Q fragments pre-scaled by Dh^-0.5 * log2(e) (softmax via exp2)
    const float qscale = 0.125f * 1.44269504088896f;
    v8bf qf[2][2];
    #pragma unroll
    for (int mt = 0; mt < 2; mt++) {
        int pq = sbase + (qoff + mt * 16 + ln15) * r;
        #pragma unroll
        for (int ks = 0; ks < 2; ks++) {
            v8bf qv = (pq < TOK_L)
                ? *(const v8bf*)(qb_ + (size_t)(b * TOK_L + pq) * QKVS + ks * 32 + q4 * 8)
                : zero8();
            #pragma unroll
            for (int i = 0; i < 8; i++) qv[i] = (bf16)((float)qv[i] * qscale);
            qf[mt][ks] = qv;
        }
    }
    v4f o[2][4];
    float lsum[2][4];
    #pragma unroll
    for (int mt = 0; mt < 2; mt++)
        #pragma unroll
        for (int g2 = 0; g2 < 4; g2++) lsum[mt][g2] = 0.f;
    #pragma unroll
    for (int mt = 0; mt < 2; mt++)
        #pragma unroll
        for (int dt = 0; dt < 4; dt++) o[mt][dt] = zero4();

    const bf16* vtb = Vt + (size_t)(yy * 24 + bh) * 12 * 4096;
    bf16* plw = &pl[wid][0];

    stageK(0, 0);
    __syncthreads();

    for (int kt = 0; kt < kt_lim; kt++) {
        const int cur = kt & 1;
        if (kt + 1 < kt_lim) stageK(kt + 1, cur ^ 1);
        if (wactive) {
            const bf16* klc = kl + cur * 4096;
            v8bf kf[4][2];
            #pragma unroll
            for (int nt = 0; nt < 4; nt++)
                #pragma unroll
                for (int ks = 0; ks < 2; ks++)
                    kf[nt][ks] = *(const v8bf*)(klc + (nt * 2 + ks) * 512 + lane * 8);
            v4f s[2][4];
            #pragma unroll
            for (int mt = 0; mt < 2; mt++)
                #pragma unroll
                for (int nt = 0; nt < 4; nt++) {
                    s[mt][nt] = __builtin_amdgcn_mfma_f32_16x16x32_bf16(qf[mt][0], kf[nt][0], zero4(), 0, 0, 0);
                    s[mt][nt] = __builtin_amdgcn_mfma_f32_16x16x32_bf16(qf[mt][1], kf[nt][1], s[mt][nt], 0, 0, 0);
                }
            bool vm[4];
            #pragma unroll
            for (int nt = 0; nt < 4; nt++)
                vm[nt] = (kt * 64 + nt * 16 + ln15) < n_valid;
            #pragma unroll
            for (int mt = 0; mt < 2; mt++) {
                #pragma unroll
                for (int g2 = 0; g2 < 4; g2++) {
                    int rowq4 = q4 * 4 + g2;               // rowq & 15
                    #pragma unroll
                    for (int nt = 0; nt < 4; nt++) {
                        float p = vm[nt] ? exp2f(s[mt][nt][g2]) : 0.f;
                        lsum[mt][g2] += p;
                        // A-frag placement: frag (mt, ks=nt>>1), lane'' chunk
                        int q4p = (nt * 2 + (ln15 >> 3)) & 3;
                        plw[((mt * 2 + (nt >> 1)) << 9) + ((q4p * 16 + rowq4) << 3) + (ln15 & 7)] = (bf16)p;
                    }
                }
            }
            #pragma unroll
            for (int ks = 0; ks < 2; ks++) {
                v8bf pa[2], vf[4];
                #pragma unroll
                for (int mt = 0; mt < 2; mt++)
                    pa[mt] = *(const v8bf*)(plw + ((mt * 2 + ks) << 9) + lane * 8);
                #pragma unroll
                for (int dt = 0; dt < 4; dt++)
                    vf[dt] = *(const v8bf*)(vtb + (size_t)kt * 4096 + (dt * 2 + ks) * 512 + lane * 8);
                #pragma unroll
                for (int mt = 0; mt < 2; mt++)
                    #pragma unroll
                    for (int dt = 0; dt < 4; dt++)
                        o[mt][dt] = __builtin_amdgcn_mfma_f32_16x16x32_bf16(pa[mt], vf[dt], o[mt][dt], 0, 0, 0);
            }
        }
        __syncthreads();
    }
    if (!wactive) return;

    bf16* od = (br == 0) ? oac : obr + (size_t)(br - 1) * HSZ;
    #pragma unroll
    for (int mt = 0; mt < 2; mt++) {
        #pragma unroll
        for (int g2 = 0; g2 < 4; g2++) {
            float l = lsum[mt][g2];
            l += __shfl_xor(l, 1, 64);
            l += __shfl_xor(l, 2, 64);
            l += __shfl_xor(l, 4, 64);
            l += __shfl_xor(l, 8, 64);
            l += pad_add;
            int row = mt * 16 + q4 * 4 + g2;
            int pq = sbase + (qoff + row) * r;
            if (pq >= TOK_L) continue;
            float linv = 1.f / l;
            if (ln15 == 0)
                lse5[(size_t)br * MHC + (size_t)(b * TOK_L + pq) * NH + hd] = __logf(l);
            #pragma unroll
            for (int dt = 0; dt < 4; dt++)
                od[(size_t)(b * TOK_L + pq) * EMB + hd * DH + dt * 16 + ln15] =
                    (bf16)(o[mt][dt][g2] * linv);
        }
    }
}

// ---------------------------------------------------------------------------
// LSE-softmax recombination of the 5 branches -> hn (bf16, next GEMM's A).
// ---------------------------------------------------------------------------
__global__ __launch_bounds__(256) void attn_combine(
    const bf16* __restrict__ oac, const bf16* __restrict__ obr,
    const float* __restrict__ lse5, bf16* __restrict__ outb)
{
    size_t e = (size_t)blockIdx.x * 256 + threadIdx.x;
    if (e >= HSZ) return;
    size_t g = e >> 6;
    int h = (int)(g % NH);
    int p = (int)((g / NH) % TOK_L);
    float l0 = lse5[g];
    float m = l0;
    float lv[4];
    bool cov[4];
    #pragma unroll
    for (int j = 0; j < 4; j++) {
        int r = 2 << j;
        int gsz = (NH + r - 1) / r;
        cov[j] = ((p & (r - 1)) == (h / gsz));
        if (cov[j]) {
            lv[j] = lse5[(size_t)(j + 1) * MHC + g];
            m = fmaxf(m, lv[j]);
        }
    }
    float w0 = __expf(l0 - m);
    float wsum = w0;
    float acc = w0 * (float)oac[e];
    #pragma unroll
    for (int j = 0; j < 4; j++) {
        if (cov[j]) {
            float wj = __expf(lv[j] - m);
            wsum += wj;
            acc = fmaf(wj, (float)obr[(size_t)j * HSZ + e], acc);
        }
    }
    outb[e] = (bf16)(acc / wsum);
}

// out[b,c] = hn[b,0,:] @ head_w + head_b   (hn bf16, head fp32)
__global__ __launch_bounds__(256) void head_kernel(
    const bf16* __restrict__ hn, const float* __restrict__ hw,
    const float* __restrict__ hb, float* __restrict__ out)
{
    int b = blockIdx.y;
    int c = blockIdx.x * 256 + threadIdx.x;
    __shared__ float srow[EMB];
    for (int e = threadIdx.x; e < EMB; e += 256)
        srow[e] = (float)hn[(size_t)b * TOK_L * EMB + e];
    __syncthreads();
    if (c < 1000) {
        float acc = hb[c];
        for (int e = 0; e < EMB; e++)
            acc = fmaf(srow[e], hw[(size_t)e * 1000 + c], acc);
        out[b * 1000 + c] = acc;
    }
}

// ---------------------------------------------------------------------------
extern "C" void kernel_launch(void* const* d_in, const int* in_sizes, int n_in,
                              void* d_out, int out_size, void* d_ws, size_t ws_size,
                              hipStream_t stream)
{
    const float* x       = (const float*)d_in[0];
    const float* patch_w = (const float*)d_in[1];
    const float* patch_b = (const float*)d_in[2];
    const float* cls_tok = (const float*)d_in[3];
    const float* pos_emb = (const float*)d_in[4];
    const float* ln1_g   = (const float*)d_in[5];
    const float* ln1_b   = (const float*)d_in[6];
    const float* wq      = (const float*)d_in[7];
    const float* bq      = (const float*)d_in[8];
    const float* wk      = (const float*)d_in[9];
    const float* bk      = (const float*)d_in[10];
    const float* wv      = (const float*)d_in[11];
    const float* bv      = (const float*)d_in[12];
    const float* wo      = (const float*)d_in[13];
    const float* bo      = (const float*)d_in[14];
    const float* ln2_g   = (const float*)d_in[15];
    const float* ln2_b   = (const float*)d_in[16];
    const float* w1      = (const float*)d_in[17];
    const float* b1      = (const float*)d_in[18];
    const float* w2      = (const float*)d_in[19];
    const float* b2      = (const float*)d_in[20];
    const float* normf_g = (const float*)d_in[21];
    const float* normf_b = (const float*)d_in[22];
    const float* head_w  = (const float*)d_in[23];
    const float* head_b  = (const float*)d_in[24];
    float* out = (float*)d_out;

    char* wp = (char*)d_ws;
    auto alloc = [&](size_t bytes) { char* r = wp; wp += (bytes + 255) & ~(size_t)255; return r; };
    float* h    = (float*)alloc(HSZ * 4);
    bf16*  hn   = (bf16*)alloc(HSZ * 2);
    bf16*  QKV  = (bf16*)alloc((size_t)BATCH * TOK_L * QKVS * 2);
    bf16*  oac  = (bf16*)alloc(HSZ * 2);
    float* lse5 = (float*)alloc(5 * MHC * 4);
    bf16*  Vt   = (bf16*)alloc((size_t)12 * 24 * 12 * 4096 * 2);
    bf16*  mid  = (bf16*)alloc(4 * HSZ * 2);       // FFN mid / Xp / obr overlay
    bf16*  obr  = mid;
    bf16*  Xp   = mid;

    bf16*  qkv_t0 = (bf16*)alloc((size_t)2 * QKVS * 768 * 2);
    bf16*  wo_t0  = (bf16*)alloc((size_t)2 * 768 * 768 * 2);
    bf16*  w1_t   = (bf16*)alloc((size_t)2 * 3072 * 768 * 2);
    bf16*  w2_t   = (bf16*)alloc((size_t)2 * 768 * 3072 * 2);
    bf16*  pw_b   = (bf16*)alloc((size_t)768 * 1024 * 2);
    float* bqkv   = (float*)alloc((size_t)2 * QKVS * 4);

    const int M = BATCH * TOK_L;        // 6146
    const int MT = (M + 127) / 128;     // 49

    prep_weights<<<dim3(14592), 256, 0, stream>>>(wq, wk, wv, wo, w1, w2, patch_w,
                                                  qkv_t0, wo_t0, w1_t, w2_t, pw_b);
    prep_small<<<dim3(18), 256, 0, stream>>>(bq, bk, bv, bqkv, cls_tok, pos_emb, h);

    gather_patches<<<dim3(BATCH * 3072), 256, 0, stream>>>(x, Xp);
    gemm_bf16<64><<<dim3(12, 48), 256, 0, stream>>>(Xp, pw_b, patch_b, h, nullptr,
                                                    BATCH * 3072, 768, 1024, 4, pos_emb);

    for (int layer = 0; layer < 2; layer++) {
        size_t bOff  = (size_t)layer * 768;
        size_t b1Off = (size_t)layer * 3072;
        bf16* qt   = qkv_t0 + (size_t)layer * QKVS * 768;
        bf16* wo_t = wo_t0 + (size_t)layer * 589824;

        layernorm_kernel<<<dim3(M), 256, 0, stream>>>(h, ln1_g + bOff, ln1_b + bOff, hn, M);
        gemm_bf16<128><<<dim3(18, MT), 256, 0, stream>>>(hn, qt, bqkv + (size_t)layer * QKVS,
                                                         nullptr, QKV, M, QKVS, 768, 8, nullptr);

        pack_vt<<<dim3(12, 12, 24), 256, 0, stream>>>(QKV, Vt);
        attn_mfma<<<dim3(1728), 256, 0, stream>>>(QKV, Vt, oac, obr, lse5);
        attn_combine<<<dim3((unsigned)((HSZ + 255) / 256)), 256, 0, stream>>>(oac, obr, lse5, hn);

        gemm_bf16<64><<<dim3(12, MT), 256, 0, stream>>>(hn, wo_t, bo + bOff, h, nullptr,
                                                        M, 768, 768, 1, nullptr);

        layernorm_kernel<<<dim3(M), 256, 0, stream>>>(h, ln2_g + bOff, ln2_b + bOff, hn, M);
        gemm_bf16<128><<<dim3(24, MT), 256, 0, stream>>>(hn, w1_t + (size_t)layer * 2359296, b1 + b1Off,
                                                         nullptr, mid, M, 3072, 768, 8 | 2, nullptr);
        gemm_bf16<64><<<dim3(12, MT), 256, 0, stream>>>(mid, w2_t + (size_t)layer * 2359296, b2 + bOff,
                                                        h, nullptr, M, 768, 3072, 1, nullptr);
    }

    layernorm_kernel<<<dim3(M), 256, 0, stream>>>(h, normf_g, normf_b, hn, M);
    head_kernel<<<dim3(4, BATCH), 256, 0, stream>>>(hn, head_w, head_b, out);
}

// Round 9
// 1149.417 us; speedup vs baseline: 1.0267x; 1.0267x over previous
//
#include <hip/hip_runtime.h>
#include <math.h>

#define TOK_L 3073
#define EMB 768
#define NH 12
#define DH 64
#define BATCH 2
#define QKVS 2304
#define HSZ ((size_t)BATCH * TOK_L * EMB)   // 4,720,128
#define MHC ((size_t)BATCH * TOK_L * NH)    // 73,752

typedef __bf16 bf16;
typedef __bf16 v8bf __attribute__((ext_vector_type(8)));
typedef __bf16 v4bf __attribute__((ext_vector_type(4)));
typedef float  v4f  __attribute__((ext_vector_type(4)));

__device__ __forceinline__ v8bf zero8() {
    v8bf v;
    #pragma unroll
    for (int i = 0; i < 8; i++) v[i] = (bf16)0.f;
    return v;
}
__device__ __forceinline__ v4f zero4() {
    v4f v; v[0] = 0.f; v[1] = 0.f; v[2] = 0.f; v[3] = 0.f; return v;
}
__device__ __forceinline__ float gelu_f(float x) {
    return 0.5f * x * (1.0f + erff(x * 0.70710678118654752f));
}
// async global->LDS: lane l writes 16B at (uniform base) + l*16
__device__ __forceinline__ void gload16(const bf16* g, bf16* l) {
    __builtin_amdgcn_global_load_lds(
        (const __attribute__((address_space(1))) void*)g,
        (__attribute__((address_space(3))) void*)l, 16, 0, 0);
}

// ---------------------------------------------------------------------------
// Mega weight-prep: 12 transpose-converts + patch_w cvt. grid = 14592.
// ---------------------------------------------------------------------------
__device__ __forceinline__ void convT_tile(const float* __restrict__ src,
                                           bf16* __restrict__ dst,
                                           int K, int N, int tx, int ty)
{
    __shared__ float t[32][33];
    int n0 = tx * 32, k0 = ty * 32;
    int r = threadIdx.x >> 3, c4 = (threadIdx.x & 7) * 4;
    float4 v = *(const float4*)(src + (size_t)(k0 + r) * N + n0 + c4);
    t[r][c4 + 0] = v.x; t[r][c4 + 1] = v.y; t[r][c4 + 2] = v.z; t[r][c4 + 3] = v.w;
    __syncthreads();
    v4bf o;
    o[0] = (bf16)t[c4 + 0][r]; o[1] = (bf16)t[c4 + 1][r];
    o[2] = (bf16)t[c4 + 2][r]; o[3] = (bf16)t[c4 + 3][r];
    *(v4bf*)(dst + (size_t)(n0 + r) * K + k0 + c4) = o;
}

__global__ __launch_bounds__(256) void prep_weights(
    const float* __restrict__ wq, const float* __restrict__ wk,
    const float* __restrict__ wv, const float* __restrict__ wo,
    const float* __restrict__ w1, const float* __restrict__ w2,
    const float* __restrict__ patch_w,
    bf16* __restrict__ qkv_t0, bf16* __restrict__ wo_t0,
    bf16* __restrict__ w1_t, bf16* __restrict__ w2_t, bf16* __restrict__ pw_b)
{
    int bid = blockIdx.x;
    if (bid >= 13824) {
        int i = ((bid - 13824) * 256 + threadIdx.x) * 4;
        float4 v = *(const float4*)(patch_w + i);
        v4bf o; o[0] = (bf16)v.x; o[1] = (bf16)v.y; o[2] = (bf16)v.z; o[3] = (bf16)v.w;
        *(v4bf*)(pw_b + i) = o;
        return;
    }
    int layer = bid / 6912, t = bid % 6912;
    if (t < 1728) {
        int m = t / 576, tt = t % 576;
        const float* src = (m == 0 ? wq : m == 1 ? wk : wv) + (size_t)layer * 589824;
        bf16* dst = qkv_t0 + (size_t)layer * QKVS * 768 + (size_t)m * 589824;
        convT_tile(src, dst, 768, 768, tt % 24, tt / 24);
    } else if (t < 2304) {
        int tt = t - 1728;
        convT_tile(wo + (size_t)layer * 589824, wo_t0 + (size_t)layer * 589824,
                   768, 768, tt % 24, tt / 24);
    } else if (t < 4608) {
        int tt = t - 2304;
        convT_tile(w1 + (size_t)layer * 2359296, w1_t + (size_t)layer * 2359296,
                   768, 3072, tt % 96, tt / 96);
    } else {
        int tt = t - 4608;
        convT_tile(w2 + (size_t)layer * 2359296, w2_t + (size_t)layer * 2359296,
                   3072, 768, tt % 24, tt / 24);
    }
}

// concat q/k/v biases -> bqkv[layer][2304]; also init cls rows of h. grid 18.
__global__ __launch_bounds__(256) void prep_small(const float* __restrict__ bq,
    const float* __restrict__ bk, const float* __restrict__ bv, float* __restrict__ d,
    const float* __restrict__ cls, const float* __restrict__ pos, float* __restrict__ h)
{
    int i = blockIdx.x * 256 + threadIdx.x;
    if (i < 2 * QKVS) {
        int layer = i / QKVS, j = i % QKVS;
        const float* s = (j < 768) ? bq : (j < 1536) ? bk : bv;
        d[i] = s[(size_t)layer * 768 + (j & 767)];
    }
    if (i < 2 * 768) {
        int b = i / 768, e = i % 768;
        h[(size_t)b * TOK_L * EMB + e] = cls[e] + pos[e];
    }
}

// ---------------------------------------------------------------------------
// Patch gather: x (B,1,48,256,256) fp32 -> Xp (B*3072, 1024) bf16
// ---------------------------------------------------------------------------
__global__ __launch_bounds__(256) void gather_patches(const float* __restrict__ x,
                                                      bf16* __restrict__ Xp) {
    int p = blockIdx.x;
    int b = p / 3072, pp = p % 3072;
    int px = pp >> 8, py = (pp >> 4) & 15, pz = pp & 15;
    for (int k = threadIdx.x; k < 1024; k += 256) {
        int pd = k >> 8, ph = (k >> 4) & 15, pw = k & 15;
        size_t src = ((size_t)(b * 48 + px * 4 + pd)) * 65536
                   + (size_t)(py * 16 + ph) * 256 + (size_t)(pz * 16 + pw);
        Xp[(size_t)p * 1024 + k] = (bf16)x[src];
    }
}

// ---------------------------------------------------------------------------
// bf16 MFMA GEMM, 128xBN tile, BK=32, fragment-order LDS staging, double-
// buffered async K-loop. Split-K via blockIdx.z (kLen per split).
// flags: 1 acc into Cf, 2 gelu, 8 bf16 out, 16 fp32 partial out (no bias)
// ---------------------------------------------------------------------------
template<int BN>
__global__ __launch_bounds__(256) void gemm_bf16(
    const bf16* __restrict__ A, const bf16* __restrict__ Bt,
    const float* __restrict__ bias, float* __restrict__ Cf,
    bf16* __restrict__ Cb, float* __restrict__ Cp,
    int M, int N, int K, int kLen, int flags)
{
    __shared__ bf16 As[2][128 * 32];
    __shared__ bf16 Bs[2][BN * 32];
    const int tid = threadIdx.x;
    const int lane = tid & 63, wid = tid >> 6;
    const int ln15 = lane & 15, q4 = lane >> 4;
    const int m0 = blockIdx.y * 128, n0 = blockIdx.x * BN;
    const int kBase = blockIdx.z * kLen;
    const int wm = (wid & 1) * 64, wn = (wid >> 1) * (BN / 2);
    const int NF = BN / 32;
    const int lrow = lane & 15, lchunk = lane >> 4;

    auto stage = [&](int k0, int bufi) {
        #pragma unroll
        for (int fi = 0; fi < 2; fi++) {
            int f = wid * 2 + fi;
            int gm = m0 + f * 16 + lrow; if (gm >= M) gm = M - 1;
            gload16(A + (size_t)gm * K + kBase + k0 + lchunk * 8, As[bufi] + f * 512);
        }
        if (BN == 128) {
            #pragma unroll
            for (int fi = 0; fi < 2; fi++) {
                int f = wid * 2 + fi;
                gload16(Bt + (size_t)(n0 + f * 16 + lrow) * K + kBase + k0 + lchunk * 8,
                        Bs[bufi] + f * 512);
            }
        } else {
            gload16(Bt + (size_t)(n0 + wid * 16 + lrow) * K + kBase + k0 + lchunk * 8,
                    Bs[bufi] + wid * 512);
        }
    };

    v4f acc[4][NF];
    #pragma unroll
    for (int i = 0; i < 4; i++)
        #pragma unroll
        for (int j = 0; j < NF; j++) acc[i][j] = zero4();

    const int nsteps = kLen >> 5;
    stage(0, 0);
    for (int s = 0; s < nsteps; s++) {
        const int cur = s & 1;
        __syncthreads();
        if (s + 1 < nsteps) stage((s + 1) << 5, cur ^ 1);
        v8bf af[4], bfr[NF];
        #pragma unroll
        for (int mt = 0; mt < 4; mt++)
            af[mt] = *(const v8bf*)(As[cur] + ((wid & 1) * 4 + mt) * 512 + lane * 8);
        #pragma unroll
        for (int nt = 0; nt < NF; nt++)
            bfr[nt] = *(const v8bf*)(Bs[cur] + ((wid >> 1) * NF + nt) * 512 + lane * 8);
        #pragma unroll
        for (int mt = 0; mt < 4; mt++)
            #pragma unroll
            for (int nt = 0; nt < NF; nt++)
                acc[mt][nt] = __builtin_amdgcn_mfma_f32_16x16x32_bf16(af[mt], bfr[nt], acc[mt][nt], 0, 0, 0);
    }
    const size_t MN = (size_t)M * N;
    #pragma unroll
    for (int mt = 0; mt < 4; mt++) {
        #pragma unroll
        for (int nt = 0; nt < NF; nt++) {
            #pragma unroll
            for (int g = 0; g < 4; g++) {
                int row = m0 + wm + mt * 16 + q4 * 4 + g;
                if (row >= M) continue;
                int col = n0 + wn + nt * 16 + ln15;
                size_t ci = (size_t)row * N + col;
                if (flags & 16) {                       // fp32 partial, no bias
                    Cp[(size_t)blockIdx.z * MN + ci] = acc[mt][nt][g];
                    continue;
                }
                float v = acc[mt][nt][g] + bias[col];
                if (flags & 2) v = gelu_f(v);
                if (flags & 8) Cb[ci] = (bf16)v;
                else { if (flags & 1) v += Cf[ci]; Cf[ci] = v; }
            }
        }
    }
}

// ---------------------------------------------------------------------------
// Split-K reduce. mode 0: h[i] += bias + sum(P_k[i])    (residual GEMMs)
//                 mode 1: h[remap(row)] = sum + bias + pos (patch embed)
// ---------------------------------------------------------------------------
__global__ __launch_bounds__(256) void reduce_split(
    const float* __restrict__ P, int nsplit, int M, int N,
    const float* __restrict__ bias, float* __restrict__ h,
    const float* __restrict__ pos, int mode)
{
    size_t i4 = (size_t)blockIdx.x * 256 + threadIdx.x;
    size_t tot = (size_t)M * (N >> 2);
    if (i4 >= tot) return;
    int row = (int)(i4 / (N >> 2));
    int c4 = (int)(i4 % (N >> 2)) * 4;
    size_t off = (size_t)row * N + c4;
    size_t MN = (size_t)M * N;
    float4 s = *(const float4*)(P + off);
    for (int k = 1; k < nsplit; k++) {
        float4 p = *(const float4*)(P + (size_t)k * MN + off);
        s.x += p.x; s.y += p.y; s.z += p.z; s.w += p.w;
    }
    float4 bv = *(const float4*)(bias + c4);
    s.x += bv.x; s.y += bv.y; s.z += bv.z; s.w += bv.w;
    if (mode == 0) {
        float4 hv = *(const float4*)(h + off);
        s.x += hv.x; s.y += hv.y; s.z += hv.z; s.w += hv.w;
        *(float4*)(h + off) = s;
    } else {
        int orow = row + row / 3072 + 1;
        float4 pv = *(const float4*)(pos + (size_t)((row % 3072) + 1) * N + c4);
        s.x += pv.x; s.y += pv.y; s.z += pv.z; s.w += pv.w;
        *(float4*)(h + (size_t)orow * N + c4) = s;
    }
}

// ---------------------------------------------------------------------------
// LayerNorm over last dim (768), fp32 in -> bf16 out.
// ---------------------------------------------------------------------------
__global__ __launch_bounds__(256) void layernorm_kernel(
    const float* __restrict__ x, const float* __restrict__ g,
    const float* __restrict__ bb, bf16* __restrict__ y, int nrows)
{
    int row = blockIdx.x;
    if (row >= nrows) return;
    int tid = threadIdx.x;
    const float* xr = x + (size_t)row * EMB;
    float v0 = xr[tid], v1 = xr[tid + 256], v2 = xr[tid + 512];
    __shared__ float red[256];
    red[tid] = v0 + v1 + v2;
    __syncthreads();
    for (int o = 128; o > 0; o >>= 1) { if (tid < o) red[tid] += red[tid + o]; __syncthreads(); }
    float mu = red[0] * (1.f / 768.f);
    __syncthreads();
    float d0 = v0 - mu, d1 = v1 - mu, d2 = v2 - mu;
    red[tid] = d0 * d0 + d1 * d1 + d2 * d2;
    __syncthreads();
    for (int o = 128; o > 0; o >>= 1) { if (tid < o) red[tid] += red[tid + o]; __syncthreads(); }
    float rs = rsqrtf(red[0] * (1.f / 768.f) + 1e-5f);
    bf16* yr = y + (size_t)row * EMB;
    yr[tid]       = (bf16)(d0 * rs * g[tid]       + bb[tid]);
    yr[tid + 256] = (bf16)(d1 * rs * g[tid + 256] + bb[tid + 256]);
    yr[tid + 512] = (bf16)(d2 * rs * g[tid + 512] + bb[tid + 512]);
}

// ---------------------------------------------------------------------------
// Pack V per branch-slot in PV B-FRAGMENT order:
// Vt[(yy*24+bh)*12 + kt][frag(dt,ks)][lane][8] — attn reads contiguous 1KB.
// ---------------------------------------------------------------------------
__global__ __launch_bounds__(256) void pack_vt(const bf16* __restrict__ qkv,
                                               bf16* __restrict__ Vt)
{
    __shared__ bf16 t[64 * 65];
    int yy = blockIdx.y;
    int br, seg;
    if (yy < 5)       { br = 0; seg = yy; }
    else if (yy < 8)  { br = 1; seg = yy - 5; }
    else if (yy < 10) { br = 2; seg = yy - 8; }
    else if (yy == 10){ br = 3; seg = 0; }
    else              { br = 4; seg = 0; }
    const int r = 1 << br, w = 768 << br;
    const int gsz = (NH + r - 1) / r;
    const int bh = blockIdx.z;
    const int b = bh / NH, hd = bh % NH;
    const int off = hd / gsz;
    const int kbase = seg * w + off;
    const int kt = blockIdx.x;
    const int tid = threadIdx.x;
    const int dq = (tid & 7) * 8;
    #pragma unroll
    for (int p = 0; p < 2; p++) {
        int jl = (tid >> 3) + p * 32;
        int pk = kbase + (kt * 64 + jl) * r;
        v8bf val = (pk < TOK_L)
            ? *(const v8bf*)(qkv + (size_t)(b * TOK_L + pk) * QKVS + 1536 + hd * DH + dq)
            : zero8();
        #pragma unroll
        for (int i = 0; i < 8; i++) t[jl * 65 + dq + i] = val[i];
    }
    __syncthreads();
    size_t base = ((size_t)(yy * 24 + bh) * 12 + kt) * 4096;
    #pragma unroll
    for (int p = 0; p < 2; p++) {
        int cc = p * 256 + tid;                 // chunk 0..511
        int f = cc >> 6, lanei = cc & 63;
        int dt = f >> 1, ks = f & 1;
        int dh = dt * 16 + (lanei & 15);
        int k0e = ks * 32 + (lanei >> 4) * 8;
        v8bf o;
        #pragma unroll
        for (int i = 0; i < 8; i++) o[i] = t[(k0e + i) * 65 + dh];
        *(v8bf*)(Vt + base + (size_t)cc * 8) = o;
    }
}

// ---------------------------------------------------------------------------
// MFMA dilated attention. K tiles staged async in B-fragment order (double-
// buffered, conflict-free reads); P scratch in A-fragment order; V read from
// fragment-order Vt (contiguous global). Padded keys masked analytically.
// ---------------------------------------------------------------------------
__global__ __launch_bounds__(256) void attn_mfma(
    const bf16* __restrict__ qkv, const bf16* __restrict__ Vt,
    bf16* __restrict__ oac, bf16* __restrict__ obr, float* __restrict__ lse5)
{
    __shared__ bf16 kl[2 * 4096];        // 2 buffers x 8 frags x 512
    __shared__ bf16 pl[4][2048];         // per-wave: 4 frags x 512
    const int tid = threadIdx.x;
    const int lane = tid & 63, wid = tid >> 6;
    const int ln15 = lane & 15, q4 = lane >> 4;
    const int lrow = lane & 15, lchunk = lane >> 4;
    const int bid = blockIdx.x;
    const int xcd = bid & 7, rest = bid >> 3;
    const int slot = rest / 6, t = rest - slot * 6;
    const int g = (slot << 3) | xcd;          // 0..287
    const int yy = g / 24, bh = g - yy * 24;
    int br, seg;
    if (yy < 5)       { br = 0; seg = yy; }
    else if (yy < 8)  { br = 1; seg = yy - 5; }
    else if (yy < 10) { br = 2; seg = yy - 8; }
    else if (yy == 10){ br = 3; seg = 0; }
    else              { br = 4; seg = 0; }
    const int r = 1 << br, w = 768 << br;
    const int gsz = (NH + r - 1) / r;
    const int b = bh / NH, hd = bh % NH;
    const int off = hd / gsz;
    const int sbase = seg * w + off;
    if (sbase + (t * 128) * r >= TOK_L) return;     // block-uniform early exit

    int n_valid = (TOK_L - sbase + r - 1) / r;
    if (n_valid > 768) n_valid = 768;
    const int kt_lim = (n_valid + 63) >> 6;
    const float pad_add = (float)(768 - n_valid);
    const int qoff = t * 128 + wid * 32;
    const bool wactive = (sbase + qoff * r) < TOK_L;

    const bf16* qb_ = qkv + hd * DH;
    const bf16* kb_ = qkv + 768 + hd * DH;

    // stage K tile ktv into buffer bufi, fragment order (frag = nt*2+ks)
    auto stageK = [&](int ktv, int bufi) {
        #pragma unroll
        for (int fi = 0; fi < 2; fi++) {
            int f = wid * 2 + fi;
            int pk = sbase + (ktv * 64 + (f >> 1) * 16 + lrow) * r;
            if (pk >= TOK_L) pk = 0;                // garbage row; masked later
            gload16(kb_ + (size_t)(b * TOK_L + pk) * QKVS + (f & 1) * 32 + lchunk * 8,
                    kl + bufi * 4096 + f * 512);
        }
    };

    // Q fragments pre-scaled by Dh^-0.5 * log2(e) (softmax via exp2)
    const float qscale = 0.125f * 1.44269504088896f;
    v8bf qf[2][2];
    #pragma unroll
    for (int mt = 0; mt < 2; mt++) {
        int pq = sbase + (qoff + mt * 16 + ln15) * r;
        #pragma unroll
        for (int ks = 0; ks < 2; ks++) {
            v8bf qv = (pq < TOK_L)
                ? *(const v8bf*)(qb_ + (size_t)(b * TOK_L + pq) * QKVS + ks * 32 + q4 * 8)
                : zero8();
            #pragma unroll
            for (int i = 0; i < 8; i++) qv[i] = (bf16)((float)qv[i] * qscale);
            qf[mt][ks] = qv;
        }
    }
    v4f o[2][4];
    float lsum[2][4];
    #pragma unroll
    for (int mt = 0; mt < 2; mt++)
        #pragma unroll
        for (int g2 = 0; g2 < 4; g2++) lsum[mt][g2] = 0.f;
    #pragma unroll
    for (int mt = 0; mt < 2; mt++)
        #pragma unroll
        for (int dt = 0; dt < 4; dt++) o[mt][dt] = zero4();

    const bf16* vtb = Vt + (size_t)(yy * 24 + bh) * 12 * 4096;
    bf16* plw = &pl[wid][0];

    stageK(0, 0);
    __syncthreads();

    for (int kt = 0; kt < kt_lim; kt++) {
        const int cur = kt & 1;
        if (kt + 1 < kt_lim) stageK(kt + 1, cur ^ 1);
        if (wactive) {
            const bf16* klc = kl + cur * 4096;
            v8bf kf[4][2];
            #pragma unroll
            for (int nt = 0; nt < 4; nt++)
                #pragma unroll
                for (int ks = 0; ks < 2; ks++)
                    kf[nt][ks] = *(const v8bf*)(klc + (nt * 2 + ks) * 512 + lane * 8);
            v4f s[2][4];
            #pragma unroll
            for (int mt = 0; mt < 2; mt++)
                #pragma unroll
                for (int nt = 0; nt < 4; nt++) {
                    s[mt][nt] = __builtin_amdgcn_mfma_f32_16x16x32_bf16(qf[mt][0], kf[nt][0], zero4(), 0, 0, 0);
                    s[mt][nt] = __builtin_amdgcn_mfma_f32_16x16x32_bf16(qf[mt][1], kf[nt][1], s[mt][nt], 0, 0, 0);
                }
            bool vm[4];
            #pragma unroll
            for (int nt = 0; nt < 4; nt++)
                vm[nt] = (kt * 64 + nt * 16 + ln15) < n_valid;
            #pragma unroll
            for (int mt = 0; mt < 2; mt++) {
                #pragma unroll
                for (int g2 = 0; g2 < 4; g2++) {
                    int rowq4 = q4 * 4 + g2;               // rowq & 15
                    #pragma unroll
                    for (int nt = 0; nt < 4; nt++) {
                        float p = vm[nt] ? exp2f(s[mt][nt][g2]) : 0.f;
                        lsum[mt][g2] += p;
                        // A-frag placement: frag (mt, ks=nt>>1), lane'' chunk
                        int q4p = (nt * 2 + (ln15 >> 3)) & 3;
                        plw[((mt * 2 + (nt >> 1)) << 9) + ((q4p * 16 + rowq4) << 3) + (ln15 & 7)] = (bf16)p;
                    }
                }
            }
            #pragma unroll
            for (int ks = 0; ks < 2; ks++) {
                v8bf pa[2], vf[4];
                #pragma unroll
                for (int mt = 0; mt < 2; mt++)
                    pa[mt] = *(const v8bf*)(plw + ((mt * 2 + ks) << 9) + lane * 8);
                #pragma unroll
                for (int dt = 0; dt < 4; dt++)
                    vf[dt] = *(const v8bf*)(vtb + (size_t)kt * 4096 + (dt * 2 + ks) * 512 + lane * 8);
                #pragma unroll
                for (int mt = 0; mt < 2; mt++)
                    #pragma unroll
                    for (int dt = 0; dt < 4; dt++)
                        o[mt][dt] = __builtin_amdgcn_mfma_f32_16x16x32_bf16(pa[mt], vf[dt], o[mt][dt], 0, 0, 0);
            }
        }
        __syncthreads();
    }
    if (!wactive) return;

    bf16* od = (br == 0) ? oac : obr + (size_t)(br - 1) * HSZ;
    #pragma unroll
    for (int mt = 0; mt < 2; mt++) {
        #pragma unroll
        for (int g2 = 0; g2 < 4; g2++) {
            float l = lsum[mt][g2];
            l += __shfl_xor(l, 1, 64);
            l += __shfl_xor(l, 2, 64);
            l += __shfl_xor(l, 4, 64);
            l += __shfl_xor(l, 8, 64);
            l += pad_add;
            int row = mt * 16 + q4 * 4 + g2;
            int pq = sbase + (qoff + row) * r;
            if (pq >= TOK_L) continue;
            float linv = 1.f / l;
            if (ln15 == 0)
                lse5[(size_t)br * MHC + (size_t)(b * TOK_L + pq) * NH + hd] = __logf(l);
            #pragma unroll
            for (int dt = 0; dt < 4; dt++)
                od[(size_t)(b * TOK_L + pq) * EMB + hd * DH + dt * 16 + ln15] =
                    (bf16)(o[mt][dt][g2] * linv);
        }
    }
}

// ---------------------------------------------------------------------------
// LSE-softmax recombination of the 5 branches -> hn (bf16, next GEMM's A).
// ---------------------------------------------------------------------------
__global__ __launch_bounds__(256) void attn_combine(
    const bf16* __restrict__ oac, const bf16* __restrict__ obr,
    const float* __restrict__ lse5, bf16* __restrict__ outb)
{
    size_t e = (size_t)blockIdx.x * 256 + threadIdx.x;
    if (e >= HSZ) return;
    size_t g = e >> 6;
    int h = (int)(g % NH);
    int p = (int)((g / NH) % TOK_L);
    float l0 = lse5[g];
    float m = l0;
    float lv[4];
    bool cov[4];
    #pragma unroll
    for (int j = 0; j < 4; j++) {
        int r = 2 << j;
        int gsz = (NH + r - 1) / r;
        cov[j] = ((p & (r - 1)) == (h / gsz));
        if (cov[j]) {
            lv[j] = lse5[(size_t)(j + 1) * MHC + g];
            m = fmaxf(m, lv[j]);
        }
    }
    float w0 = __expf(l0 - m);
    float wsum = w0;
    float acc = w0 * (float)oac[e];
    #pragma unroll
    for (int j = 0; j < 4; j++) {
        if (cov[j]) {
            float wj = __expf(lv[j] - m);
            wsum += wj;
            acc = fmaf(wj, (float)obr[(size_t)j * HSZ + e], acc);
        }
    }
    outb[e] = (bf16)(acc / wsum);
}

// out[b,c] = hn[b,0,:] @ head_w + head_b   (hn bf16, head fp32)
__global__ __launch_bounds__(256) void head_kernel(
    const bf16* __restrict__ hn, const float* __restrict__ hw,
    const float* __restrict__ hb, float* __restrict__ out)
{
    int b = blockIdx.y;
    int c = blockIdx.x * 256 + threadIdx.x;
    __shared__ float srow[EMB];
    for (int e = threadIdx.x; e < EMB; e += 256)
        srow[e] = (float)hn[(size_t)b * TOK_L * EMB + e];
    __syncthreads();
    if (c < 1000) {
        float acc = hb[c];
        for (int e = 0; e < EMB; e++)
            acc = fmaf(srow[e], hw[(size_t)e * 1000 + c], acc);
        out[b * 1000 + c] = acc;
    }
}

// ---------------------------------------------------------------------------
extern "C" void kernel_launch(void* const* d_in, const int* in_sizes, int n_in,
                              void* d_out, int out_size, void* d_ws, size_t ws_size,
                              hipStream_t stream)
{
    const float* x       = (const float*)d_in[0];
    const float* patch_w = (const float*)d_in[1];
    const float* patch_b = (const float*)d_in[2];
    const float* cls_tok = (const float*)d_in[3];
    const float* pos_emb = (const float*)d_in[4];
    const float* ln1_g   = (const float*)d_in[5];
    const float* ln1_b   = (const float*)d_in[6];
    const float* wq      = (const float*)d_in[7];
    const float* bq      = (const float*)d_in[8];
    const float* wk      = (const float*)d_in[9];
    const float* bk      = (const float*)d_in[10];
    const float* wv      = (const float*)d_in[11];
    const float* bv      = (const float*)d_in[12];
    const float* wo      = (const float*)d_in[13];
    const float* bo      = (const float*)d_in[14];
    const float* ln2_g   = (const float*)d_in[15];
    const float* ln2_b   = (const float*)d_in[16];
    const float* w1      = (const float*)d_in[17];
    const float* b1      = (const float*)d_in[18];
    const float* w2      = (const float*)d_in[19];
    const float* b2      = (const float*)d_in[20];
    const float* normf_g = (const float*)d_in[21];
    const float* normf_b = (const float*)d_in[22];
    const float* head_w  = (const float*)d_in[23];
    const float* head_b  = (const float*)d_in[24];
    float* out = (float*)d_out;

    char* wp = (char*)d_ws;
    auto alloc = [&](size_t bytes) { char* r = wp; wp += (bytes + 255) & ~(size_t)255; return r; };
    float* h    = (float*)alloc(HSZ * 4);
    bf16*  hn   = (bf16*)alloc(HSZ * 2);
    bf16*  QKV  = (bf16*)alloc((size_t)BATCH * TOK_L * QKVS * 2);
    bf16*  oac  = (bf16*)alloc(HSZ * 2);
    float* lse5 = (float*)alloc(5 * MHC * 4);
    bf16*  Vt   = (bf16*)alloc((size_t)12 * 24 * 12 * 4096 * 2);
    bf16*  mid  = (bf16*)alloc(4 * HSZ * 2);       // FFN mid / Xp / obr overlay
    bf16*  obr  = mid;
    bf16*  Xp   = mid;
    float* Pbuf = (float*)alloc((size_t)3 * 6146 * 768 * 4);   // split-K partials

    bf16*  qkv_t0 = (bf16*)alloc((size_t)2 * QKVS * 768 * 2);
    bf16*  wo_t0  = (bf16*)alloc((size_t)2 * 768 * 768 * 2);
    bf16*  w1_t   = (bf16*)alloc((size_t)2 * 3072 * 768 * 2);
    bf16*  w2_t   = (bf16*)alloc((size_t)2 * 768 * 3072 * 2);
    bf16*  pw_b   = (bf16*)alloc((size_t)768 * 1024 * 2);
    float* bqkv   = (float*)alloc((size_t)2 * QKVS * 4);

    const int M = BATCH * TOK_L;        // 6146
    const int MT = (M + 127) / 128;     // 49
    const int RG  = (int)((M * 192 + 255) / 256);        // reduce grid M x N/4
    const int RGp = (int)((6144 * 192 + 255) / 256);

    prep_weights<<<dim3(14592), 256, 0, stream>>>(wq, wk, wv, wo, w1, w2, patch_w,
                                                  qkv_t0, wo_t0, w1_t, w2_t, pw_b);
    prep_small<<<dim3(18), 256, 0, stream>>>(bq, bk, bv, bqkv, cls_tok, pos_emb, h);

    gather_patches<<<dim3(BATCH * 3072), 256, 0, stream>>>(x, Xp);
    // patch embed, split-K=2 (K=1024 -> 2x512)
    gemm_bf16<64><<<dim3(12, 48, 2), 256, 0, stream>>>(Xp, pw_b, nullptr, nullptr,
                                                       nullptr, Pbuf, 6144, 768, 1024, 512, 16);
    reduce_split<<<dim3(RGp), 256, 0, stream>>>(Pbuf, 2, 6144, 768, patch_b, h, pos_emb, 1);

    for (int layer = 0; layer < 2; layer++) {
        size_t bOff  = (size_t)layer * 768;
        size_t b1Off = (size_t)layer * 3072;
        bf16* qt   = qkv_t0 + (size_t)layer * QKVS * 768;
        bf16* wo_t = wo_t0 + (size_t)layer * 589824;

        layernorm_kernel<<<dim3(M), 256, 0, stream>>>(h, ln1_g + bOff, ln1_b + bOff, hn, M);
        gemm_bf16<128><<<dim3(18, MT, 1), 256, 0, stream>>>(hn, qt, bqkv + (size_t)layer * QKVS,
                                                            nullptr, QKV, nullptr, M, QKVS, 768, 768, 8);

        pack_vt<<<dim3(12, 12, 24), 256, 0, stream>>>(QKV, Vt);
        attn_mfma<<<dim3(1728), 256, 0, stream>>>(QKV, Vt, oac, obr, lse5);
        attn_combine<<<dim3((unsigned)((HSZ + 255) / 256)), 256, 0, stream>>>(oac, obr, lse5, hn);

        // wo, split-K=2 (K=768 -> 2x384), then residual reduce into h
        gemm_bf16<64><<<dim3(12, MT, 2), 256, 0, stream>>>(hn, wo_t, nullptr, nullptr,
                                                           nullptr, Pbuf, M, 768, 768, 384, 16);
        reduce_split<<<dim3(RG), 256, 0, stream>>>(Pbuf, 2, M, 768, bo + bOff, h, nullptr, 0);

        layernorm_kernel<<<dim3(M), 256, 0, stream>>>(h, ln2_g + bOff, ln2_b + bOff, hn, M);
        gemm_bf16<128><<<dim3(24, MT, 1), 256, 0, stream>>>(hn, w1_t + (size_t)layer * 2359296, b1 + b1Off,
                                                            nullptr, mid, nullptr, M, 3072, 768, 768, 8 | 2);
        // w2, split-K=3 (K=3072 -> 3x1024), then residual reduce into h
        gemm_bf16<64><<<dim3(12, MT, 3), 256, 0, stream>>>(mid, w2_t + (size_t)layer * 2359296, nullptr,
                                                           nullptr, nullptr, Pbuf, M, 768, 3072, 1024, 16);
        reduce_split<<<dim3(RG), 256, 0, stream>>>(Pbuf, 3, M, 768, b2 + bOff, h, nullptr, 0);
    }

    layernorm_kernel<<<dim3(M), 256, 0, stream>>>(h, normf_g, normf_b, hn, M);
    head_kernel<<<dim3(4, BATCH), 256, 0, stream>>>(hn, head_w, head_b, out);
}